// Round 6
// baseline (92.571 us; speedup 1.0000x reference)
//
#include <hip/hip_runtime.h>
#include <float.h>

#define NROWS  50000
#define NF     32
#define NTREES 300
#define NINT   63
#define NLEAF  64
#define LRATE  0.1f
#define RPB    256     // rows per block == threads per block
#define TPG    30      // trees per group (multiple of 6 for ILP-6, 3 classes)
#define TG     10      // tree groups; TPG*TG == NTREES
#define SORTN  1024    // per-feature padded sorted threshold count

// ---------- prep kernel 1: per-feature sorted threshold lists ----------
// one block per feature: collect matching thresholds, bitonic-sort in LDS.
// compaction order is nondeterministic (LDS atomic) but the SORT canonicalizes
// the array (equal elements are bit-identical) -> deterministic output.
__global__ __launch_bounds__(256) void gb_sortf(const int* __restrict__ feat,
                                                const float* __restrict__ thr,
                                                float* __restrict__ sorted_all) {
    __shared__ float buf[SORTN];
    __shared__ int cnt;
    const int f = blockIdx.x;
    const int t = threadIdx.x;
    if (t == 0) cnt = 0;
    for (int i = t; i < SORTN; i += 256) buf[i] = FLT_MAX;   // +INF pad
    __syncthreads();
    for (int j = t; j < NTREES * NINT; j += 256) {
        if (feat[j] == f) {
            int p = atomicAdd(&cnt, 1);
            buf[p] = thr[j];                 // expected ~590 << SORTN
        }
    }
    __syncthreads();
    // bitonic sort ascending over SORTN
    for (int k = 2; k <= SORTN; k <<= 1) {
        for (int jj = k >> 1; jj > 0; jj >>= 1) {
            for (int i = t; i < SORTN; i += 256) {
                int ixj = i ^ jj;
                if (ixj > i) {
                    float a = buf[i], b = buf[ixj];
                    bool up = ((i & k) == 0);
                    if ((a > b) == up) { buf[i] = b; buf[ixj] = a; }
                }
            }
            __syncthreads();
        }
    }
    for (int i = t; i < SORTN; i += 256) sorted_all[f * SORTN + i] = buf[i];
}

// ---------- prep kernel 2: pack nodes as (strict_rank << 5) | feature ----------
__global__ __launch_bounds__(256) void gb_pack(const int* __restrict__ feat,
                                               const float* __restrict__ thr,
                                               const float* __restrict__ sorted_all,
                                               unsigned* __restrict__ pack) {
    int k = blockIdx.x * 256 + threadIdx.x;
    if (k >= NTREES * 64) return;
    int m = k >> 6, n = k & 63;
    unsigned v = 0;
    if (n < NINT) {
        int i = m * NINT + n;
        int f = feat[i];
        float tv = thr[i];
        const float* s = sorted_all + f * SORTN;
        int idx = 0;                          // lower_bound: #{s < tv}
        #pragma unroll
        for (int st = SORTN / 2; st >= 1; st >>= 1) {
            int c = idx + st;
            if (s[c - 1] < tv) idx = c;
        }
        v = ((unsigned)idx << 5) | (unsigned)f;
    }
    pack[k] = v;
}

// ---------- prep kernel 3: rank every x value; also init d_out ----------
__global__ __launch_bounds__(256) void gb_rank_rows(const float* __restrict__ x,
                                                    const float* __restrict__ sorted_all,
                                                    const float* __restrict__ initp,
                                                    unsigned short* __restrict__ xr,
                                                    float* __restrict__ out) {
    __shared__ float s[SORTN];                 // 4 KB -> high occupancy
    const int f = blockIdx.y;
    const int t = threadIdx.x;
    for (int i = t; i < SORTN; i += 256) s[i] = sorted_all[f * SORTN + i];
    __syncthreads();
    int row = blockIdx.x * 256 + t;
    if (row < NROWS) {
        float xv = x[(size_t)row * NF + f];
        int idx = 0;                           // L(x) = #{s < x}
        #pragma unroll
        for (int st = SORTN / 2; st >= 1; st >>= 1) {
            int c = idx + st;
            if (s[c - 1] < xv) idx = c;
        }
        xr[(size_t)f * NROWS + row] = (unsigned short)idx;
        if (f == 0) {                          // fold output init here
            out[row * 3 + 0] = initp[0];
            out[row * 3 + 1] = initp[1];
            out[row * 3 + 2] = initp[2];
        }
    }
}

// ---------- main kernel: integer-rank tree walk ----------
// x > t  <=>  L(x) > lt  (exact for strict-rank maps; ties go left as sklearn)
__global__ __launch_bounds__(RPB, 6) void gb_forest(
    const unsigned short* __restrict__ xr,    // [NF][NROWS] ranks
    const unsigned*       __restrict__ pack,  // [NTREES][64] packed nodes
    const float*          __restrict__ leaves,// [NTREES][64]
    float*                __restrict__ out)   // [NROWS][3]
{
    // 16384 + 7680 = 24064 B -> 6 blocks/CU (24 waves/CU)
    __shared__ unsigned short xs[NF][RPB];    // read bank-free (2-way)
    __shared__ unsigned nodes[TPG][64];

    const int tid  = threadIdx.x;
    const int r0   = blockIdx.x * RPB;
    const int m0   = blockIdx.y * TPG;
    const int grow = r0 + tid;
    const int gr   = grow < NROWS ? grow : NROWS - 1;

    #pragma unroll
    for (int f = 0; f < NF; ++f) xs[f][tid] = xr[(size_t)f * NROWS + gr];
    for (int i = tid; i < TPG * 64; i += RPB)
        ((unsigned*)nodes)[i] = pack[m0 * 64 + i];
    __syncthreads();

    float acc0 = 0.f, acc1 = 0.f, acc2 = 0.f;
    #pragma unroll
    for (int g = 0; g < TPG; g += 6) {
        unsigned jj[6] = {0, 0, 0, 0, 0, 0};   // fully unrolled -> registers
        #pragma unroll
        for (int d = 0; d < 6; ++d) {
            #pragma unroll
            for (int c = 0; c < 6; ++c) {
                unsigned nd = nodes[g + c][jj[c]];        // ds_read_b32
                unsigned xv = xs[nd & 31u][tid];          // ds_read_u16
                jj[c] = 2u * jj[c] + 1u + (xv > (nd >> 5) ? 1u : 0u);
            }
        }
        #pragma unroll
        for (int c = 0; c < 6; ++c) {
            float lv = leaves[(size_t)(m0 + g + c) * NLEAF + (jj[c] - NINT)];
            if (c % 3 == 0)      acc0 += lv;
            else if (c % 3 == 1) acc1 += lv;
            else                 acc2 += lv;
        }
    }

    if (grow < NROWS) {
        atomicAdd(&out[grow * 3 + 0], LRATE * acc0);
        atomicAdd(&out[grow * 3 + 1], LRATE * acc1);
        atomicAdd(&out[grow * 3 + 2], LRATE * acc2);
    }
}

// ---------- fallback (ws too small): round-2 style f32 kernel ----------
__global__ void gb_init_out(const float* __restrict__ initp,
                            float* __restrict__ out, int n) {
    int i = blockIdx.x * blockDim.x + threadIdx.x;
    if (i < n) out[i] = initp[i % 3];
}

__global__ __launch_bounds__(RPB, 4) void gb_forest_fb(
    const float* __restrict__ x, const int* __restrict__ feat,
    const float* __restrict__ thr, const float* __restrict__ leaves,
    float* __restrict__ out) {
    __shared__ float xsf[NF][RPB];
    __shared__ int2  nodesf[12][64];
    const int tid = threadIdx.x;
    const int r0 = blockIdx.x * RPB;
    const int m0 = blockIdx.y * 12;
    const int grow = r0 + tid;
    {
        const float4* xrp = (const float4*)x + (size_t)(grow < NROWS ? grow : NROWS - 1) * (NF / 4);
        float4 v[8];
        #pragma unroll
        for (int k = 0; k < 8; ++k) v[k] = xrp[k];
        #pragma unroll
        for (int k = 0; k < 8; ++k) {
            xsf[k*4+0][tid] = v[k].x; xsf[k*4+1][tid] = v[k].y;
            xsf[k*4+2][tid] = v[k].z; xsf[k*4+3][tid] = v[k].w;
        }
    }
    for (int i = tid; i < 12 * NINT; i += RPB) {
        int tl = i / NINT, nd = i - tl * NINT;
        int gi = (m0 + tl) * NINT + nd;
        nodesf[tl][nd] = make_int2(feat[gi], __float_as_int(thr[gi]));
    }
    __syncthreads();
    float acc0 = 0.f, acc1 = 0.f, acc2 = 0.f;
    for (int it = 0; it < 12; it += 6) {
        int idx[6] = {0,0,0,0,0,0};
        #pragma unroll
        for (int d = 0; d < 6; ++d) {
            #pragma unroll
            for (int j = 0; j < 6; ++j) {
                int2 nd = nodesf[it + j][idx[j]];
                idx[j] = 2*idx[j] + 1 + (int)(xsf[nd.x][tid] > __int_as_float(nd.y));
            }
        }
        #pragma unroll
        for (int j = 0; j < 6; ++j) {
            float lv = leaves[(m0 + it + j) * NLEAF + (idx[j] - NINT)];
            if (j % 3 == 0) acc0 += lv; else if (j % 3 == 1) acc1 += lv; else acc2 += lv;
        }
    }
    if (grow < NROWS) {
        atomicAdd(&out[grow*3+0], LRATE*acc0);
        atomicAdd(&out[grow*3+1], LRATE*acc1);
        atomicAdd(&out[grow*3+2], LRATE*acc2);
    }
}

extern "C" void kernel_launch(void* const* d_in, const int* in_sizes, int n_in,
                              void* d_out, int out_size, void* d_ws, size_t ws_size,
                              hipStream_t stream) {
    const float* x      = (const float*)d_in[0];
    const int*   feat   = (const int*)d_in[1];
    const float* thr    = (const float*)d_in[2];
    const float* leaves = (const float*)d_in[3];
    const float* initp  = (const float*)d_in[4];
    float* out = (float*)d_out;

    // ws layout: sorted[32][1024] f32 | pack[300*64] u32 | xr[32][50000] u16
    const size_t off_pack = (size_t)NF * SORTN * 4;                 // 131072
    const size_t off_xr   = off_pack + (size_t)NTREES * 64 * 4;     // 207872
    const size_t need     = off_xr + (size_t)NF * NROWS * 2;        // 3407872

    if (ws_size >= need) {
        float*          sorted_all = (float*)d_ws;
        unsigned*       pack       = (unsigned*)((char*)d_ws + off_pack);
        unsigned short* xr         = (unsigned short*)((char*)d_ws + off_xr);

        gb_sortf<<<NF, 256, 0, stream>>>(feat, thr, sorted_all);
        gb_pack<<<(NTREES * 64 + 255) / 256, 256, 0, stream>>>(feat, thr, sorted_all, pack);
        dim3 g3((NROWS + 255) / 256, NF);
        gb_rank_rows<<<g3, 256, 0, stream>>>(x, sorted_all, initp, xr, out);
        dim3 grid((NROWS + RPB - 1) / RPB, TG);
        gb_forest<<<grid, RPB, 0, stream>>>(xr, pack, leaves, out);
    } else {
        gb_init_out<<<(out_size + 255) / 256, 256, 0, stream>>>(initp, out, out_size);
        dim3 grid((NROWS + RPB - 1) / RPB, 25);
        gb_forest_fb<<<grid, RPB, 0, stream>>>(x, feat, thr, leaves, out);
    }
}